// Round 13
// baseline (16554.485 us; speedup 1.0000x reference)
//
#include <hip/hip_runtime.h>
#include <math.h>

#define D_IN  1024
#define H_DIM 2048
#define H3    6144
#define T_SEQ 4096
#define S_SEQ 4095

#define NREP  16          // replicas; publish stays 1 coalesced burst each

// ---------------------------------------------------------------------------
// Tiled fp32 GEMM: C[M,N] = op(A)[M,K] @ B[N,K]^T + bias[N]
// ---------------------------------------------------------------------------
#define TS 64
#define KS 16
#define LSTR 68

__global__ __launch_bounds__(256) void gemm_bias(
    const float* __restrict__ A, const float* __restrict__ B,
    const float* __restrict__ bias, float* __restrict__ C,
    int M, int N, int K, int lda, int Atrans)
{
    __shared__ __align__(16) float As[KS * LSTR];
    __shared__ __align__(16) float Bs[KS * LSTR];
    const int tid = threadIdx.x;
    const int m0 = blockIdx.x * TS;
    const int n0 = blockIdx.y * TS;
    const int tx = tid & 15, ty = tid >> 4;
    float c[4][4] = {};

    for (int k0 = 0; k0 < K; k0 += KS) {
        if (Atrans) {
            const int ml = tid & 63;
            const int kb = tid >> 6;
            #pragma unroll
            for (int kk = 0; kk < KS; kk += 4) {
                const int m = m0 + ml;
                As[(kk + kb) * LSTR + ml] =
                    (m < M) ? A[(size_t)(k0 + kk + kb) * lda + m] : 0.f;
            }
        } else {
            const int kl = tid & 15;
            const int mb = tid >> 4;
            #pragma unroll
            for (int ml = 0; ml < TS; ml += 16) {
                const int m = m0 + ml + mb;
                As[kl * LSTR + ml + mb] =
                    (m < M) ? A[(size_t)m * lda + (k0 + kl)] : 0.f;
            }
        }
        {
            const int kl = tid & 15;
            const int nb = tid >> 4;
            #pragma unroll
            for (int nl = 0; nl < TS; nl += 16) {
                Bs[kl * LSTR + nl + nb] = B[(size_t)(n0 + nl + nb) * K + (k0 + kl)];
            }
        }
        __syncthreads();
        #pragma unroll
        for (int kk = 0; kk < KS; ++kk) {
            const float4 a = *(const float4*)&As[kk * LSTR + tx * 4];
            const float4 b = *(const float4*)&Bs[kk * LSTR + ty * 4];
            c[0][0] += a.x * b.x; c[0][1] += a.x * b.y; c[0][2] += a.x * b.z; c[0][3] += a.x * b.w;
            c[1][0] += a.y * b.x; c[1][1] += a.y * b.y; c[1][2] += a.y * b.z; c[1][3] += a.y * b.w;
            c[2][0] += a.z * b.x; c[2][1] += a.z * b.y; c[2][2] += a.z * b.z; c[2][3] += a.z * b.w;
            c[3][0] += a.w * b.x; c[3][1] += a.w * b.y; c[3][2] += a.w * b.z; c[3][3] += a.w * b.w;
        }
        __syncthreads();
    }
    #pragma unroll
    for (int i = 0; i < 4; ++i) {
        const int m = m0 + tx * 4 + i;
        if (m < M) {
            #pragma unroll
            for (int j = 0; j < 4; ++j) {
                const int n = n0 + ty * 4 + j;
                C[(size_t)m * N + n] = c[i][j] + bias[n];
            }
        }
    }
}

// ---------------------------------------------------------------------------
// W_h2h fp32 -> bf16, block-major relayout (block b: 24 contiguous rows).
// ---------------------------------------------------------------------------
__device__ inline unsigned short f2bf(float f) {
    union { float f; unsigned u; } a; a.f = f;
    unsigned u = a.u;
    u += 0x7fffu + ((u >> 16) & 1u);
    return (unsigned short)(u >> 16);
}

__global__ __launch_bounds__(256) void conv_whh(
    const float* __restrict__ Whh, unsigned short* __restrict__ wbf)
{
    const int g = blockIdx.x * 256 + threadIdx.x;
    const size_t base = (size_t)g * 4;
    const int b   = (int)(base / 49152);
    const int rem = (int)(base % 49152);
    const int r   = rem / 2048;
    const int k   = rem % 2048;
    const size_t srow = ((size_t)(8 * b + r / 3 + (r % 3) * H_DIM)) * H_DIM + k;
    const float4 v = *(const float4*)(Whh + srow);
    ushort4 o;
    o.x = f2bf(v.x); o.y = f2bf(v.y); o.z = f2bf(v.z); o.w = f2bf(v.w);
    *(ushort4*)(wbf + base) = o;
}

// ---------------------------------------------------------------------------
// Wide MALL-coherent poll load: 2 x 16B, bypassing L1/L2 (sc0 sc1).
// ---------------------------------------------------------------------------
__device__ inline void load8_mall(const unsigned* rp, uint4& a, uint4& b) {
    asm volatile(
        "global_load_dwordx4 %0, %2, off sc0 sc1\n\t"
        "global_load_dwordx4 %1, %3, off sc0 sc1\n\t"
        "s_waitcnt vmcnt(0)"
        : "=&v"(a), "=&v"(b)
        : "v"(rp), "v"(rp + 4)
        : "memory");
}

__device__ inline float u2f(unsigned v) { return __uint_as_float(v & 0xffff0000u); }

// 2-way bf16 dot with f32 accumulate: d = w.lo*h.lo + w.hi*h.hi + c
__device__ inline float dot2b(unsigned w, unsigned h, float c) {
    float d;
    asm("v_dot2_f32_bf16 %0, %1, %2, %3" : "=v"(d) : "v"(w), "v"(h), "v"(c));
    return d;
}

// ---------------------------------------------------------------------------
// Persistent cooperative scan (r12 + NREP=16 two-wave coalesced publish).
// 256 blocks x 256 threads, 1 block/CU. Block b owns units 8b..8b+7.
//
// h broadcast: data=flag packed words  word = (bf16(h)<<16) | (t+1),
// replicated 16x.
//   producers: gate lanes drop words into LDS scratch (hpub[8]);
//              after the pre-poll __syncthreads, waves 0-1 (tid<128) issue
//              ONE store each: lane tid -> replica tid>>3, word tid&7.
//              Each replica gets one coalesced 32B burst (no partial-line
//              RMWs; producer tail unchanged vs 8 replicas).
//   consumers: block b polls replica (b&15) (16 pollers/replica),
//              16B sc0sc1 loads + s_sleep(1) backoff.
// hs is PACKED (2 bf16/dword), consumed via v_dot2_f32_bf16.
// Parity double-buffer (2 x 2048 words/replica): publish(t+2) follows
// poll(t+1) which follows all-blocks-read-parity-p -> no overwrite race.
// ---------------------------------------------------------------------------
#define SMEM_SZ (24 * 2048 * 2 + 1024 * 4 + 96 * 4)

__global__ __launch_bounds__(256, 1) void gru_scan(
    const unsigned short* __restrict__ wbf, const float* __restrict__ bhh,
    const float* __restrict__ gx, const float* __restrict__ h0,
    float* __restrict__ log_h, unsigned* __restrict__ pbuf)
{
    extern __shared__ char smem[];
    unsigned short* wlds = (unsigned short*)smem;            // 24*2048 bf16
    unsigned* hsp = (unsigned*)(smem + 24 * 2048 * 2);       // 1024 packed (2048 bf16)
    float* gxs = (float*)(smem + 24 * 2048 * 2 + 1024 * 4);  // 2 x 32
    float* bb  = gxs + 64;                                   // 24
    unsigned* hpub = (unsigned*)(bb + 24);                   // 8 publish words

    const int tid = threadIdx.x;
    const int b = blockIdx.x;
    const int w = tid >> 6, l = tid & 63;
    const int s = (tid + b) & 255;           // slot group this thread fills
    const unsigned myrep = (unsigned)(b & (NREP - 1)) << 12; // replica polled

    // Stage weights into LDS (96 KB, coalesced 16B/lane).
    {
        const uint4* src = (const uint4*)(wbf + (size_t)b * 24 * 2048);
        uint4* dst = (uint4*)wlds;
        #pragma unroll
        for (int i = 0; i < 24; ++i) dst[tid + 256 * i] = src[tid + 256 * i];
    }
    for (int i = tid; i < H_DIM / 2; i += 256)
        hsp[i] = (unsigned)f2bf(h0[2 * i]) | ((unsigned)f2bf(h0[2 * i + 1]) << 16);
    if (tid < 24) {
        const int n = 8 * b + tid / 3 + (tid % 3) * H_DIM;
        bb[tid]  = bhh[n];
        gxs[tid] = gx[n];              // step-0 input gates (includes b_i2h)
    }
    __syncthreads();

    const int rbase = w * 6;
    for (int t = 0; t < S_SEQ; ++t) {
        // Prefetch next step's 24 gx values (consumed after the fill phase).
        float gpre = 0.f;
        const bool pf = (tid < 24) && (t + 1 < S_SEQ);
        if (pf) gpre = gx[(size_t)(t + 1) * H3 + 8 * b + tid / 3 + (tid % 3) * H_DIM];

        // Packed h chunk: lane l covers values [i*512 + l*8, +8) as uint4.
        uint4 hpk[4];
        const uint4* hs4 = (const uint4*)hsp;
        #pragma unroll
        for (int i = 0; i < 4; ++i) hpk[i] = hs4[i * 64 + l];

        // 6 row dots via v_dot2_f32_bf16 (4 independent accumulators).
        float sums[6];
        #pragma unroll
        for (int m = 0; m < 6; ++m) {
            const int r = rbase + m;
            const uint4* wrow = (const uint4*)wlds + r * 256;
            float a0 = 0.f, a1 = 0.f, a2 = 0.f, a3 = 0.f;
            #pragma unroll
            for (int i = 0; i < 4; ++i) {
                const uint4 u = wrow[i * 64 + l];
                a0 = dot2b(u.x, hpk[i].x, a0);
                a1 = dot2b(u.y, hpk[i].y, a1);
                a2 = dot2b(u.z, hpk[i].z, a2);
                a3 = dot2b(u.w, hpk[i].w, a3);
            }
            float acc = (a0 + a1) + (a2 + a3);
            #pragma unroll
            for (int off = 32; off; off >>= 1) acc += __shfl_xor(acc, off);
            sums[m] = acc;
        }

        // Gate math; packed word goes to LDS scratch (publish after barrier).
        const int p = t & 1;
        const int cur = p * 32;
        if (l < 2) {
            const int jj = 2 * w + l;
            const int mb = l * 3;
            const float h_r = sums[mb + 0] + bb[jj * 3 + 0];
            const float h_i = sums[mb + 1] + bb[jj * 3 + 1];
            const float h_n = sums[mb + 2] + bb[jj * 3 + 2];
            const float i_r = gxs[cur + jj * 3 + 0];
            const float i_i = gxs[cur + jj * 3 + 1];
            const float i_n = gxs[cur + jj * 3 + 2];
            const float rg = 1.f / (1.f + expf(-(i_r + h_r)));
            const float ig = 1.f / (1.f + expf(-(i_i + h_i)));
            const float ng = tanhf(i_n + rg * h_n);
            const int J = 8 * b + jj;
            const unsigned hw = hsp[J >> 1];
            const float hprev = __uint_as_float((J & 1) ? (hw & 0xffff0000u) : (hw << 16));
            const float hnew = ng + ig * (hprev - ng);
            const unsigned hb = (unsigned)f2bf(hnew) << 16;
            hpub[jj] = hb | (unsigned)(t + 1);
            log_h[(size_t)t * H_DIM + J] = __uint_as_float(hb);
        }

        if (t == S_SEQ - 1) break;

        const unsigned want = (unsigned)(t + 1);
        __syncthreads();   // block compute done; hpub visible; hsp consumed

        // Waves 0-1: one coalesced publish instruction covering 16 replicas
        // (lane tid -> replica tid>>3, word tid&7; 16 x 32B bursts).
        if (tid < 8 * NREP) {
            const unsigned word = hpub[tid & 7];
            const unsigned J = 8u * (unsigned)b + ((unsigned)tid & 7u);
            __hip_atomic_store(
                &pbuf[(((unsigned)tid >> 3) << 12) + ((unsigned)p << 11) + J],
                word, __ATOMIC_RELAXED, __HIP_MEMORY_SCOPE_AGENT);
        }

        // Fill phase: poll own 8 packed words, repack into hsp.
        {
            const unsigned* basep = pbuf + myrep + (p << 11) + s * 8;
            uint4 va, vb;
            for (;;) {
                load8_mall(basep, va, vb);
                const unsigned m =
                    ((va.x ^ want) | (va.y ^ want) | (va.z ^ want) | (va.w ^ want) |
                     (vb.x ^ want) | (vb.y ^ want) | (vb.z ^ want) | (vb.w ^ want)) & 0xffffu;
                if (m == 0) break;
                __builtin_amdgcn_s_sleep(1);
            }
            uint4 pk;
            pk.x = (va.x >> 16) | (va.y & 0xffff0000u);
            pk.y = (va.z >> 16) | (va.w & 0xffff0000u);
            pk.z = (vb.x >> 16) | (vb.y & 0xffff0000u);
            pk.w = (vb.z >> 16) | (vb.w & 0xffff0000u);
            ((uint4*)hsp)[s] = pk;
        }
        if (pf) gxs[(~t & 1) * 32 + tid] = gpre;
        __syncthreads();
    }
}

// ---------------------------------------------------------------------------
// Fallback per-step kernel (round-1 path).
// ---------------------------------------------------------------------------
__global__ __launch_bounds__(192) void gru_step(
    const float* __restrict__ Whh, const float* __restrict__ bhh,
    const float* __restrict__ gx_t,
    const float* __restrict__ Wih, const float* __restrict__ bih,
    const float* __restrict__ X, int t,
    const float* __restrict__ h_prev, float* __restrict__ h_out)
{
    __shared__ __align__(16) float hsl[H_DIM];
    __shared__ float red[3], gred[3];
    const int tid = threadIdx.x;
    for (int i = tid; i < H_DIM; i += 192) hsl[i] = h_prev[i];
    __syncthreads();

    const int w = tid >> 6, lane = tid & 63;
    const int j = blockIdx.x;
    const int row = j + w * H_DIM;

    const float4* Wr = (const float4*)(Whh + (size_t)row * H_DIM);
    const float4* h4 = (const float4*)hsl;
    float acc = 0.f;
    #pragma unroll
    for (int k = 0; k < H_DIM / 256; ++k) {
        const float4 wv = Wr[lane + 64 * k];
        const float4 hv = h4[lane + 64 * k];
        acc += wv.x * hv.x + wv.y * hv.y + wv.z * hv.z + wv.w * hv.w;
    }
    float gacc = 0.f;
    if (gx_t == nullptr) {
        const float* Wi = Wih + (size_t)row * D_IN;
        #pragma unroll
        for (int k = 0; k < D_IN / 64; ++k) {
            const int d = lane + 64 * k;
            gacc += Wi[d] * X[(size_t)d * T_SEQ + t];
        }
    }
    #pragma unroll
    for (int off = 32; off > 0; off >>= 1) {
        acc  += __shfl_xor(acc, off);
        gacc += __shfl_xor(gacc, off);
    }
    if (lane == 0) {
        red[w]  = acc + bhh[row];
        gred[w] = gacc + ((gx_t == nullptr) ? bih[row] : 0.f);
    }
    __syncthreads();
    if (tid == 0) {
        float i_r, i_i, i_n;
        if (gx_t) { i_r = gx_t[j]; i_i = gx_t[j + H_DIM]; i_n = gx_t[j + 2 * H_DIM]; }
        else      { i_r = gred[0]; i_i = gred[1]; i_n = gred[2]; }
        const float h_r = red[0], h_i = red[1], h_n = red[2];
        const float rg = 1.f / (1.f + expf(-(i_r + h_r)));
        const float ig = 1.f / (1.f + expf(-(i_i + h_i)));
        const float ng = tanhf(i_n + rg * h_n);
        h_out[j] = ng + ig * (hsl[j] - ng);
    }
}

// ---------------------------------------------------------------------------
// Per-step loss + Pearson correlation.
// ---------------------------------------------------------------------------
__global__ __launch_bounds__(256) void loss_acc(
    const float* __restrict__ X, const float* __restrict__ yhat_all,
    float* __restrict__ log_loss, float* __restrict__ log_acc)
{
    const int t = blockIdx.x;
    const float* yh = yhat_all + (size_t)t * D_IN;
    const int tid = threadIdx.x;
    float s_y = 0, s_p = 0, s_yy = 0, s_pp = 0, s_yp = 0, s_d2 = 0;
    for (int d = tid; d < D_IN; d += 256) {
        const float y = X[(size_t)d * T_SEQ + (t + 1)];
        const float p = yh[d];
        const float df = y - p;
        s_y += y; s_p += p; s_yy += y * y; s_pp += p * p; s_yp += y * p; s_d2 += df * df;
    }
    #pragma unroll
    for (int off = 32; off > 0; off >>= 1) {
        s_y  += __shfl_xor(s_y, off);  s_p  += __shfl_xor(s_p, off);
        s_yy += __shfl_xor(s_yy, off); s_pp += __shfl_xor(s_pp, off);
        s_yp += __shfl_xor(s_yp, off); s_d2 += __shfl_xor(s_d2, off);
    }
    __shared__ float red[4][6];
    const int w = tid >> 6;
    if ((tid & 63) == 0) {
        red[w][0] = s_y; red[w][1] = s_p; red[w][2] = s_yy;
        red[w][3] = s_pp; red[w][4] = s_yp; red[w][5] = s_d2;
    }
    __syncthreads();
    if (tid == 0) {
        float a = 0, b = 0, cc = 0, dd = 0, e = 0, f = 0;
        for (int i = 0; i < 4; ++i) {
            a += red[i][0]; b += red[i][1]; cc += red[i][2];
            dd += red[i][3]; e += red[i][4]; f += red[i][5];
        }
        const float n = (float)D_IN;
        log_loss[t] = f / n;
        const float cov = e - a * b / n;
        const float vy  = cc - a * a / n;
        const float vp  = dd - b * b / n;
        log_acc[t] = cov / (sqrtf(vy) * sqrtf(vp));
    }
}

__global__ __launch_bounds__(256) void loss_sum(
    const float* __restrict__ log_loss, float* __restrict__ out)
{
    float s = 0;
    for (int i = threadIdx.x; i < S_SEQ; i += 256) s += log_loss[i];
    #pragma unroll
    for (int off = 32; off > 0; off >>= 1) s += __shfl_xor(s, off);
    __shared__ float red[4];
    if ((threadIdx.x & 63) == 0) red[threadIdx.x >> 6] = s;
    __syncthreads();
    if (threadIdx.x == 0) out[0] = red[0] + red[1] + red[2] + red[3];
}

// ---------------------------------------------------------------------------
extern "C" void kernel_launch(void* const* d_in, const int* in_sizes, int n_in,
                              void* d_out, int out_size, void* d_ws, size_t ws_size,
                              hipStream_t stream)
{
    const float* X   = (const float*)d_in[0];
    const float* h0  = (const float*)d_in[1];
    const float* Wih = (const float*)d_in[2];
    const float* bih = (const float*)d_in[3];
    const float* Whh = (const float*)d_in[4];
    const float* bhh = (const float*)d_in[5];
    const float* Who = (const float*)d_in[6];
    const float* bho = (const float*)d_in[7];

    float* out       = (float*)d_out;
    float* loss_out  = out;
    float* log_loss  = out + 1;
    float* log_acc   = out + 1 + S_SEQ;
    float* log_h     = out + 1 + 2 * S_SEQ;
    float* log_yhat  = log_h + (size_t)S_SEQ * H_DIM;

    const size_t wbf_bytes = (size_t)256 * 24 * 2048 * sizeof(unsigned short); // 24 MB
    const size_t gx_bytes  = (size_t)S_SEQ * H3 * sizeof(float);               // ~96 MB
    const size_t pbuf_words = (size_t)NREP * 2 * 2048;                         // 16 replicas
    const size_t pbuf_bytes = pbuf_words * sizeof(unsigned);                   // 256 KB

    const bool full = (ws_size >= wbf_bytes + gx_bytes + pbuf_bytes);
    unsigned short* wbf = full ? (unsigned short*)d_ws : nullptr;
    float* gx = full ? (float*)((char*)d_ws + wbf_bytes)
                     : ((ws_size >= gx_bytes) ? (float*)d_ws : nullptr);
    unsigned* pbuf = full ? (unsigned*)((char*)d_ws + wbf_bytes + gx_bytes) : nullptr;

    // Phase 1: gx_all = x_seq @ W_i2h^T + b_i2h
    if (gx) {
        dim3 g((S_SEQ + TS - 1) / TS, H3 / TS);
        gemm_bias<<<g, 256, 0, stream>>>(X, Wih, bih, gx, S_SEQ, H3, D_IN, T_SEQ, 1);
    }

    // Phase 2: sequential scan.
    bool coop_ok = false;
    if (full) {
        hipMemsetAsync(pbuf, 0, pbuf_bytes, stream);      // deterministic slot state
        conv_whh<<<12288, 256, 0, stream>>>(Whh, wbf);
        hipFuncSetAttribute(reinterpret_cast<const void*>(gru_scan),
                            hipFuncAttributeMaxDynamicSharedMemorySize, SMEM_SZ);
        void* args[] = {(void*)&wbf, (void*)&bhh, (void*)&gx, (void*)&h0,
                        (void*)&log_h, (void*)&pbuf};
        hipError_t ce = hipLaunchCooperativeKernel(
            reinterpret_cast<const void*>(gru_scan), dim3(256), dim3(256),
            args, (unsigned int)SMEM_SZ, stream);
        coop_ok = (ce == hipSuccess);
    }
    if (!coop_ok) {
        for (int t = 0; t < S_SEQ; ++t) {
            const float* hp = (t == 0) ? h0 : (log_h + (size_t)(t - 1) * H_DIM);
            gru_step<<<H_DIM, 192, 0, stream>>>(
                Whh, bhh, gx ? gx + (size_t)t * H3 : nullptr,
                Wih, bih, X, t, hp, log_h + (size_t)t * H_DIM);
        }
    }

    // Phase 3: log_yhat = log_h @ W_h2o^T + b_h2o
    {
        dim3 g((S_SEQ + TS - 1) / TS, D_IN / TS);
        gemm_bias<<<g, 256, 0, stream>>>(log_h, Who, bho, log_yhat, S_SEQ, D_IN, H_DIM, H_DIM, 0);
    }

    // Phase 4: per-step loss + Pearson corr, then total loss.
    loss_acc<<<S_SEQ, 256, 0, stream>>>(X, log_yhat, log_loss, log_acc);
    loss_sum<<<1, 256, 0, stream>>>(log_loss, loss_out);
}

// Round 14
// 16119.325 us; speedup vs baseline: 1.0270x; 1.0270x over previous
//
#include <hip/hip_runtime.h>
#include <math.h>

#define D_IN  1024
#define H_DIM 2048
#define H3    6144
#define T_SEQ 4096
#define S_SEQ 4095

// ---------------------------------------------------------------------------
// Tiled fp32 GEMM: C[M,N] = op(A)[M,K] @ B[N,K]^T + bias[N]
// ---------------------------------------------------------------------------
#define TS 64
#define KS 16
#define LSTR 68

__global__ __launch_bounds__(256) void gemm_bias(
    const float* __restrict__ A, const float* __restrict__ B,
    const float* __restrict__ bias, float* __restrict__ C,
    int M, int N, int K, int lda, int Atrans)
{
    __shared__ __align__(16) float As[KS * LSTR];
    __shared__ __align__(16) float Bs[KS * LSTR];
    const int tid = threadIdx.x;
    const int m0 = blockIdx.x * TS;
    const int n0 = blockIdx.y * TS;
    const int tx = tid & 15, ty = tid >> 4;
    float c[4][4] = {};

    for (int k0 = 0; k0 < K; k0 += KS) {
        if (Atrans) {
            const int ml = tid & 63;
            const int kb = tid >> 6;
            #pragma unroll
            for (int kk = 0; kk < KS; kk += 4) {
                const int m = m0 + ml;
                As[(kk + kb) * LSTR + ml] =
                    (m < M) ? A[(size_t)(k0 + kk + kb) * lda + m] : 0.f;
            }
        } else {
            const int kl = tid & 15;
            const int mb = tid >> 4;
            #pragma unroll
            for (int ml = 0; ml < TS; ml += 16) {
                const int m = m0 + ml + mb;
                As[kl * LSTR + ml + mb] =
                    (m < M) ? A[(size_t)m * lda + (k0 + kl)] : 0.f;
            }
        }
        {
            const int kl = tid & 15;
            const int nb = tid >> 4;
            #pragma unroll
            for (int nl = 0; nl < TS; nl += 16) {
                Bs[kl * LSTR + nl + nb] = B[(size_t)(n0 + nl + nb) * K + (k0 + kl)];
            }
        }
        __syncthreads();
        #pragma unroll
        for (int kk = 0; kk < KS; ++kk) {
            const float4 a = *(const float4*)&As[kk * LSTR + tx * 4];
            const float4 b = *(const float4*)&Bs[kk * LSTR + ty * 4];
            c[0][0] += a.x * b.x; c[0][1] += a.x * b.y; c[0][2] += a.x * b.z; c[0][3] += a.x * b.w;
            c[1][0] += a.y * b.x; c[1][1] += a.y * b.y; c[1][2] += a.y * b.z; c[1][3] += a.y * b.w;
            c[2][0] += a.z * b.x; c[2][1] += a.z * b.y; c[2][2] += a.z * b.z; c[2][3] += a.z * b.w;
            c[3][0] += a.w * b.x; c[3][1] += a.w * b.y; c[3][2] += a.w * b.z; c[3][3] += a.w * b.w;
        }
        __syncthreads();
    }
    #pragma unroll
    for (int i = 0; i < 4; ++i) {
        const int m = m0 + tx * 4 + i;
        if (m < M) {
            #pragma unroll
            for (int j = 0; j < 4; ++j) {
                const int n = n0 + ty * 4 + j;
                C[(size_t)m * N + n] = c[i][j] + bias[n];
            }
        }
    }
}

// ---------------------------------------------------------------------------
// W_h2h fp32 -> bf16, block-major relayout (block b: 24 contiguous rows).
// ---------------------------------------------------------------------------
__device__ inline unsigned short f2bf(float f) {
    union { float f; unsigned u; } a; a.f = f;
    unsigned u = a.u;
    u += 0x7fffu + ((u >> 16) & 1u);
    return (unsigned short)(u >> 16);
}

__global__ __launch_bounds__(256) void conv_whh(
    const float* __restrict__ Whh, unsigned short* __restrict__ wbf)
{
    const int g = blockIdx.x * 256 + threadIdx.x;
    const size_t base = (size_t)g * 4;
    const int b   = (int)(base / 49152);
    const int rem = (int)(base % 49152);
    const int r   = rem / 2048;
    const int k   = rem % 2048;
    const size_t srow = ((size_t)(8 * b + r / 3 + (r % 3) * H_DIM)) * H_DIM + k;
    const float4 v = *(const float4*)(Whh + srow);
    ushort4 o;
    o.x = f2bf(v.x); o.y = f2bf(v.y); o.z = f2bf(v.z); o.w = f2bf(v.w);
    *(ushort4*)(wbf + base) = o;
}

// ---------------------------------------------------------------------------
// Wide MALL-coherent poll load: 2 x 16B, bypassing L1/L2 (sc0 sc1).
// ---------------------------------------------------------------------------
__device__ inline void load8_mall(const unsigned* rp, uint4& a, uint4& b) {
    asm volatile(
        "global_load_dwordx4 %0, %2, off sc0 sc1\n\t"
        "global_load_dwordx4 %1, %3, off sc0 sc1\n\t"
        "s_waitcnt vmcnt(0)"
        : "=&v"(a), "=&v"(b)
        : "v"(rp), "v"(rp + 4)
        : "memory");
}

__device__ inline float u2f(unsigned v) { return __uint_as_float(v & 0xffff0000u); }

// 2-way bf16 dot with f32 accumulate: d = w.lo*h.lo + w.hi*h.hi + c
__device__ inline float dot2b(unsigned w, unsigned h, float c) {
    float d;
    asm("v_dot2_f32_bf16 %0, %1, %2, %3" : "=v"(d) : "v"(w), "v"(h), "v"(c));
    return d;
}

// ---------------------------------------------------------------------------
// Persistent cooperative scan (r12 optimum: NREP=8, coalesced wave-0
// publish, packed-bf16 h + v_dot2).
// 256 blocks x 256 threads, 1 block/CU. Block b owns units 8b..8b+7.
//
// h broadcast: data=flag packed words  word = (bf16(h)<<16) | (t+1),
// replicated 8x.
//   producers: gate lanes drop words into LDS scratch (hpub[8]);
//              after the pre-poll __syncthreads, WAVE 0 issues ONE store
//              instruction: lane l -> replica l>>3, word l&7. Each replica
//              receives one coalesced 32B burst (no partial-line RMWs).
//   consumers: block b polls replica (b&7), 16B sc0sc1 loads + s_sleep(1).
// hs is PACKED (2 bf16/dword), consumed via v_dot2_f32_bf16.
// Parity double-buffer (2 x 2048 words/replica): publish(t+2) follows
// poll(t+1) which follows all-blocks-read-parity-p -> no overwrite race.
// ---------------------------------------------------------------------------
#define SMEM_SZ (24 * 2048 * 2 + 1024 * 4 + 96 * 4)

__global__ __launch_bounds__(256, 1) void gru_scan(
    const unsigned short* __restrict__ wbf, const float* __restrict__ bhh,
    const float* __restrict__ gx, const float* __restrict__ h0,
    float* __restrict__ log_h, unsigned* __restrict__ pbuf)
{
    extern __shared__ char smem[];
    unsigned short* wlds = (unsigned short*)smem;            // 24*2048 bf16
    unsigned* hsp = (unsigned*)(smem + 24 * 2048 * 2);       // 1024 packed (2048 bf16)
    float* gxs = (float*)(smem + 24 * 2048 * 2 + 1024 * 4);  // 2 x 32
    float* bb  = gxs + 64;                                   // 24
    unsigned* hpub = (unsigned*)(bb + 24);                   // 8 publish words

    const int tid = threadIdx.x;
    const int b = blockIdx.x;
    const int w = tid >> 6, l = tid & 63;
    const int s = (tid + b) & 255;           // slot group this thread fills
    const unsigned myrep = (unsigned)(b & 7) << 12;  // replica this block polls

    // Stage weights into LDS (96 KB, coalesced 16B/lane).
    {
        const uint4* src = (const uint4*)(wbf + (size_t)b * 24 * 2048);
        uint4* dst = (uint4*)wlds;
        #pragma unroll
        for (int i = 0; i < 24; ++i) dst[tid + 256 * i] = src[tid + 256 * i];
    }
    for (int i = tid; i < H_DIM / 2; i += 256)
        hsp[i] = (unsigned)f2bf(h0[2 * i]) | ((unsigned)f2bf(h0[2 * i + 1]) << 16);
    if (tid < 24) {
        const int n = 8 * b + tid / 3 + (tid % 3) * H_DIM;
        bb[tid]  = bhh[n];
        gxs[tid] = gx[n];              // step-0 input gates (includes b_i2h)
    }
    __syncthreads();

    const int rbase = w * 6;
    for (int t = 0; t < S_SEQ; ++t) {
        // Prefetch next step's 24 gx values (consumed after the fill phase).
        float gpre = 0.f;
        const bool pf = (tid < 24) && (t + 1 < S_SEQ);
        if (pf) gpre = gx[(size_t)(t + 1) * H3 + 8 * b + tid / 3 + (tid % 3) * H_DIM];

        // Packed h chunk: lane l covers values [i*512 + l*8, +8) as uint4.
        uint4 hpk[4];
        const uint4* hs4 = (const uint4*)hsp;
        #pragma unroll
        for (int i = 0; i < 4; ++i) hpk[i] = hs4[i * 64 + l];

        // 6 row dots via v_dot2_f32_bf16 (4 independent accumulators).
        float sums[6];
        #pragma unroll
        for (int m = 0; m < 6; ++m) {
            const int r = rbase + m;
            const uint4* wrow = (const uint4*)wlds + r * 256;
            float a0 = 0.f, a1 = 0.f, a2 = 0.f, a3 = 0.f;
            #pragma unroll
            for (int i = 0; i < 4; ++i) {
                const uint4 u = wrow[i * 64 + l];
                a0 = dot2b(u.x, hpk[i].x, a0);
                a1 = dot2b(u.y, hpk[i].y, a1);
                a2 = dot2b(u.z, hpk[i].z, a2);
                a3 = dot2b(u.w, hpk[i].w, a3);
            }
            float acc = (a0 + a1) + (a2 + a3);
            #pragma unroll
            for (int off = 32; off; off >>= 1) acc += __shfl_xor(acc, off);
            sums[m] = acc;
        }

        // Gate math; packed word goes to LDS scratch (publish after barrier).
        const int p = t & 1;
        const int cur = p * 32;
        if (l < 2) {
            const int jj = 2 * w + l;
            const int mb = l * 3;
            const float h_r = sums[mb + 0] + bb[jj * 3 + 0];
            const float h_i = sums[mb + 1] + bb[jj * 3 + 1];
            const float h_n = sums[mb + 2] + bb[jj * 3 + 2];
            const float i_r = gxs[cur + jj * 3 + 0];
            const float i_i = gxs[cur + jj * 3 + 1];
            const float i_n = gxs[cur + jj * 3 + 2];
            const float rg = 1.f / (1.f + expf(-(i_r + h_r)));
            const float ig = 1.f / (1.f + expf(-(i_i + h_i)));
            const float ng = tanhf(i_n + rg * h_n);
            const int J = 8 * b + jj;
            const unsigned hw = hsp[J >> 1];
            const float hprev = __uint_as_float((J & 1) ? (hw & 0xffff0000u) : (hw << 16));
            const float hnew = ng + ig * (hprev - ng);
            const unsigned hb = (unsigned)f2bf(hnew) << 16;
            hpub[jj] = hb | (unsigned)(t + 1);
            log_h[(size_t)t * H_DIM + J] = __uint_as_float(hb);
        }

        if (t == S_SEQ - 1) break;

        const unsigned want = (unsigned)(t + 1);
        __syncthreads();   // block compute done; hpub visible; hsp consumed

        // Wave 0: ONE coalesced publish instruction covering all 8 replicas
        // (lane l -> replica l>>3, word l&7; 8 x 32B bursts).
        if (tid < 64) {
            const unsigned word = hpub[tid & 7];
            const unsigned J = 8u * (unsigned)b + ((unsigned)tid & 7u);
            __hip_atomic_store(
                &pbuf[(((unsigned)tid >> 3) << 12) + ((unsigned)p << 11) + J],
                word, __ATOMIC_RELAXED, __HIP_MEMORY_SCOPE_AGENT);
        }

        // Fill phase: poll own 8 packed words, repack into hsp.
        {
            const unsigned* basep = pbuf + myrep + (p << 11) + s * 8;
            uint4 va, vb;
            for (;;) {
                load8_mall(basep, va, vb);
                const unsigned m =
                    ((va.x ^ want) | (va.y ^ want) | (va.z ^ want) | (va.w ^ want) |
                     (vb.x ^ want) | (vb.y ^ want) | (vb.z ^ want) | (vb.w ^ want)) & 0xffffu;
                if (m == 0) break;
                __builtin_amdgcn_s_sleep(1);
            }
            uint4 pk;
            pk.x = (va.x >> 16) | (va.y & 0xffff0000u);
            pk.y = (va.z >> 16) | (va.w & 0xffff0000u);
            pk.z = (vb.x >> 16) | (vb.y & 0xffff0000u);
            pk.w = (vb.z >> 16) | (vb.w & 0xffff0000u);
            ((uint4*)hsp)[s] = pk;
        }
        if (pf) gxs[(~t & 1) * 32 + tid] = gpre;
        __syncthreads();
    }
}

// ---------------------------------------------------------------------------
// Fallback per-step kernel (round-1 path).
// ---------------------------------------------------------------------------
__global__ __launch_bounds__(192) void gru_step(
    const float* __restrict__ Whh, const float* __restrict__ bhh,
    const float* __restrict__ gx_t,
    const float* __restrict__ Wih, const float* __restrict__ bih,
    const float* __restrict__ X, int t,
    const float* __restrict__ h_prev, float* __restrict__ h_out)
{
    __shared__ __align__(16) float hsl[H_DIM];
    __shared__ float red[3], gred[3];
    const int tid = threadIdx.x;
    for (int i = tid; i < H_DIM; i += 192) hsl[i] = h_prev[i];
    __syncthreads();

    const int w = tid >> 6, lane = tid & 63;
    const int j = blockIdx.x;
    const int row = j + w * H_DIM;

    const float4* Wr = (const float4*)(Whh + (size_t)row * H_DIM);
    const float4* h4 = (const float4*)hsl;
    float acc = 0.f;
    #pragma unroll
    for (int k = 0; k < H_DIM / 256; ++k) {
        const float4 wv = Wr[lane + 64 * k];
        const float4 hv = h4[lane + 64 * k];
        acc += wv.x * hv.x + wv.y * hv.y + wv.z * hv.z + wv.w * hv.w;
    }
    float gacc = 0.f;
    if (gx_t == nullptr) {
        const float* Wi = Wih + (size_t)row * D_IN;
        #pragma unroll
        for (int k = 0; k < D_IN / 64; ++k) {
            const int d = lane + 64 * k;
            gacc += Wi[d] * X[(size_t)d * T_SEQ + t];
        }
    }
    #pragma unroll
    for (int off = 32; off > 0; off >>= 1) {
        acc  += __shfl_xor(acc, off);
        gacc += __shfl_xor(gacc, off);
    }
    if (lane == 0) {
        red[w]  = acc + bhh[row];
        gred[w] = gacc + ((gx_t == nullptr) ? bih[row] : 0.f);
    }
    __syncthreads();
    if (tid == 0) {
        float i_r, i_i, i_n;
        if (gx_t) { i_r = gx_t[j]; i_i = gx_t[j + H_DIM]; i_n = gx_t[j + 2 * H_DIM]; }
        else      { i_r = gred[0]; i_i = gred[1]; i_n = gred[2]; }
        const float h_r = red[0], h_i = red[1], h_n = red[2];
        const float rg = 1.f / (1.f + expf(-(i_r + h_r)));
        const float ig = 1.f / (1.f + expf(-(i_i + h_i)));
        const float ng = tanhf(i_n + rg * h_n);
        h_out[j] = ng + ig * (hsl[j] - ng);
    }
}

// ---------------------------------------------------------------------------
// Per-step loss + Pearson correlation.
// ---------------------------------------------------------------------------
__global__ __launch_bounds__(256) void loss_acc(
    const float* __restrict__ X, const float* __restrict__ yhat_all,
    float* __restrict__ log_loss, float* __restrict__ log_acc)
{
    const int t = blockIdx.x;
    const float* yh = yhat_all + (size_t)t * D_IN;
    const int tid = threadIdx.x;
    float s_y = 0, s_p = 0, s_yy = 0, s_pp = 0, s_yp = 0, s_d2 = 0;
    for (int d = tid; d < D_IN; d += 256) {
        const float y = X[(size_t)d * T_SEQ + (t + 1)];
        const float p = yh[d];
        const float df = y - p;
        s_y += y; s_p += p; s_yy += y * y; s_pp += p * p; s_yp += y * p; s_d2 += df * df;
    }
    #pragma unroll
    for (int off = 32; off > 0; off >>= 1) {
        s_y  += __shfl_xor(s_y, off);  s_p  += __shfl_xor(s_p, off);
        s_yy += __shfl_xor(s_yy, off); s_pp += __shfl_xor(s_pp, off);
        s_yp += __shfl_xor(s_yp, off); s_d2 += __shfl_xor(s_d2, off);
    }
    __shared__ float red[4][6];
    const int w = tid >> 6;
    if ((tid & 63) == 0) {
        red[w][0] = s_y; red[w][1] = s_p; red[w][2] = s_yy;
        red[w][3] = s_pp; red[w][4] = s_yp; red[w][5] = s_d2;
    }
    __syncthreads();
    if (tid == 0) {
        float a = 0, b = 0, cc = 0, dd = 0, e = 0, f = 0;
        for (int i = 0; i < 4; ++i) {
            a += red[i][0]; b += red[i][1]; cc += red[i][2];
            dd += red[i][3]; e += red[i][4]; f += red[i][5];
        }
        const float n = (float)D_IN;
        log_loss[t] = f / n;
        const float cov = e - a * b / n;
        const float vy  = cc - a * a / n;
        const float vp  = dd - b * b / n;
        log_acc[t] = cov / (sqrtf(vy) * sqrtf(vp));
    }
}

__global__ __launch_bounds__(256) void loss_sum(
    const float* __restrict__ log_loss, float* __restrict__ out)
{
    float s = 0;
    for (int i = threadIdx.x; i < S_SEQ; i += 256) s += log_loss[i];
    #pragma unroll
    for (int off = 32; off > 0; off >>= 1) s += __shfl_xor(s, off);
    __shared__ float red[4];
    if ((threadIdx.x & 63) == 0) red[threadIdx.x >> 6] = s;
    __syncthreads();
    if (threadIdx.x == 0) out[0] = red[0] + red[1] + red[2] + red[3];
}

// ---------------------------------------------------------------------------
extern "C" void kernel_launch(void* const* d_in, const int* in_sizes, int n_in,
                              void* d_out, int out_size, void* d_ws, size_t ws_size,
                              hipStream_t stream)
{
    const float* X   = (const float*)d_in[0];
    const float* h0  = (const float*)d_in[1];
    const float* Wih = (const float*)d_in[2];
    const float* bih = (const float*)d_in[3];
    const float* Whh = (const float*)d_in[4];
    const float* bhh = (const float*)d_in[5];
    const float* Who = (const float*)d_in[6];
    const float* bho = (const float*)d_in[7];

    float* out       = (float*)d_out;
    float* loss_out  = out;
    float* log_loss  = out + 1;
    float* log_acc   = out + 1 + S_SEQ;
    float* log_h     = out + 1 + 2 * S_SEQ;
    float* log_yhat  = log_h + (size_t)S_SEQ * H_DIM;

    const size_t wbf_bytes = (size_t)256 * 24 * 2048 * sizeof(unsigned short); // 24 MB
    const size_t gx_bytes  = (size_t)S_SEQ * H3 * sizeof(float);               // ~96 MB
    const size_t pbuf_words = (size_t)8 * 2 * 2048;                            // 8 replicas
    const size_t pbuf_bytes = pbuf_words * sizeof(unsigned);                   // 128 KB

    const bool full = (ws_size >= wbf_bytes + gx_bytes + pbuf_bytes);
    unsigned short* wbf = full ? (unsigned short*)d_ws : nullptr;
    float* gx = full ? (float*)((char*)d_ws + wbf_bytes)
                     : ((ws_size >= gx_bytes) ? (float*)d_ws : nullptr);
    unsigned* pbuf = full ? (unsigned*)((char*)d_ws + wbf_bytes + gx_bytes) : nullptr;

    // Phase 1: gx_all = x_seq @ W_i2h^T + b_i2h
    if (gx) {
        dim3 g((S_SEQ + TS - 1) / TS, H3 / TS);
        gemm_bias<<<g, 256, 0, stream>>>(X, Wih, bih, gx, S_SEQ, H3, D_IN, T_SEQ, 1);
    }

    // Phase 2: sequential scan.
    bool coop_ok = false;
    if (full) {
        hipMemsetAsync(pbuf, 0, pbuf_bytes, stream);      // deterministic slot state
        conv_whh<<<12288, 256, 0, stream>>>(Whh, wbf);
        hipFuncSetAttribute(reinterpret_cast<const void*>(gru_scan),
                            hipFuncAttributeMaxDynamicSharedMemorySize, SMEM_SZ);
        void* args[] = {(void*)&wbf, (void*)&bhh, (void*)&gx, (void*)&h0,
                        (void*)&log_h, (void*)&pbuf};
        hipError_t ce = hipLaunchCooperativeKernel(
            reinterpret_cast<const void*>(gru_scan), dim3(256), dim3(256),
            args, (unsigned int)SMEM_SZ, stream);
        coop_ok = (ce == hipSuccess);
    }
    if (!coop_ok) {
        for (int t = 0; t < S_SEQ; ++t) {
            const float* hp = (t == 0) ? h0 : (log_h + (size_t)(t - 1) * H_DIM);
            gru_step<<<H_DIM, 192, 0, stream>>>(
                Whh, bhh, gx ? gx + (size_t)t * H3 : nullptr,
                Wih, bih, X, t, hp, log_h + (size_t)t * H_DIM);
        }
    }

    // Phase 3: log_yhat = log_h @ W_h2o^T + b_h2o
    {
        dim3 g((S_SEQ + TS - 1) / TS, D_IN / TS);
        gemm_bias<<<g, 256, 0, stream>>>(log_h, Who, bho, log_yhat, S_SEQ, D_IN, H_DIM, H_DIM, 0);
    }

    // Phase 4: per-step loss + Pearson corr, then total loss.
    loss_acc<<<S_SEQ, 256, 0, stream>>>(X, log_yhat, log_loss, log_acc);
    loss_sum<<<1, 256, 0, stream>>>(log_loss, loss_out);
}